// Round 17
// baseline (363.219 us; speedup 1.0000x reference)
//
#include <hip/hip_runtime.h>
#include <math.h>

namespace {
constexpr int NB = 4, NCHT = 29, NF = 19, NM = 7, NHI = 3;
constexpr int HH = 512, WW = 512;
constexpr int PH  = 170;           // pooled H/W
constexpr int NHW = 168;           // shifted-view grid
constexpr int NS  = NHW * NHW;     // 28224 samples
constexpr int NBC = NB * NCHT;     // 116
constexpr int RSTR = 176;          // padded plane row stride
constexpr int CCH  = 7;            // kCov chunks (24 rows each)

constexpr int F2M[NF] = {0,0,0,1,1,1,2,2,3,3,4,5,5,6,6,6,6,6,6};
constexpr int M2H[NM] = {0,0,1,1,1,2,2};

constexpr unsigned long long packTbl(const int* a, int n) {
  unsigned long long p = 0;
  for (int i = 0; i < n; i++) p |= (unsigned long long)(a[i]) << (3 * i);
  return p;
}
constexpr int F2H_[NF] = {0,0,0,0,0,0,1,1,1,1,1,2,2,2,2,2,2,2,2};
constexpr unsigned long long PF2M = packTbl(F2M, NF);
constexpr unsigned long long PF2H = packTbl(F2H_, NF);

// ws float layout
constexpr int    WS_S1  = 16;       // raw view sums, 116*32
constexpr int    WS_COV = 4096;     // raw upper-tri moments, 116*324
constexpr int    WS_RED = 49152;    // 64 slots * 16 floats
constexpr size_t PLANER = (size_t)NBC * PH * RSTR;   // 3,470,720 floats
constexpr size_t WS_LA  = 65536;
constexpr size_t WS_PR  = WS_LA + PLANER;
constexpr size_t WS_ZERO_BYTES = (size_t)(WS_RED + 64 * 16) * 4;
} // namespace

// async global->LDS DMA, 16B per lane; LDS dest linear in lane order,
// GLOBAL source per-lane (m104).
#define GLOAD16(gsrc, ldst)                                                     \
  __builtin_amdgcn_global_load_lds(                                             \
      (const __attribute__((address_space(1))) void*)(gsrc),                    \
      (__attribute__((address_space(3))) void*)(ldst), 16, 0, 0)

// ---------------- kernel A: logit-space hierarchy + BCE + pool ---------------
// grid (11, 171, NB), 192 thr. R14 compute verbatim; ONLY the phase-2 store
// addressing changed to plane-major [bc][wy][wx] (58 x 64B runs per block).
template <int W4>
__device__ __forceinline__ void kA_body(
    const int bx, const int wy, const int b, const int tid,
    const float* __restrict__ cls, const int* __restrict__ label,
    float* __restrict__ ws, float* sPixF, unsigned* sMask, float (*sRed)[3]) {
  constexpr int NCOL = 4 * W4;       // 48 or 32
  constexpr int CST  = 3 * NCOL;     // 144 or 96
  constexpr int T3   = 3 * W4;
  const int x0   = 48 * bx;
  const int y0   = 3 * wy;
  const int rmax = (wy == 170) ? 1 : 2;

  for (int i = tid; i < NCHT * T3; i += 192) {
    const int c   = i / T3;
    const int rem = i - c * T3;
    const int r   = rem / W4;
    const int f   = rem - r * W4;
    const int rr  = (r <= rmax) ? r : rmax;
    const float* src =
        cls + ((size_t)(b * NCHT + c) * HH + (y0 + rr)) * WW + x0 + 4 * f;
    GLOAD16(src, &sPixF[4 * i]);
  }
  __syncthreads();

  float bce0 = 0.f, bce1 = 0.f, bce2 = 0.f, cnt = 0.f;
  if (tid < CST) {
    const int r = tid / NCOL;
    if (r <= rmax) {
      const int col = tid - r * NCOL;
      const int lbl = label[((size_t)b * HH + (y0 + r)) * WW + x0 + col];
      const bool valid = (lbl != 255);
      const int lf = valid ? lbl : 0;
      const int lm = (int)((PF2M >> (3 * lf)) & 7ull);
      const int lh = (int)((PF2H >> (3 * lf)) & 7ull);
      const float vm = valid ? 1.f : 0.f;

      float x[NCHT];
      #pragma unroll
      for (int c = 0; c < NCHT; c++) x[c] = sPixF[c * CST + tid];

      float segf[NM];
      #pragma unroll
      for (int m = 0; m < NM; m++) segf[m] = -1e30f;
      #pragma unroll
      for (int f = 0; f < NF; f++) segf[F2M[f]] = fmaxf(segf[F2M[f]], x[f]);
      float pBx[NM];
      #pragma unroll
      for (int m = 0; m < NM; m++) pBx[m] = fmaxf(segf[m], x[NF + m]);
      float segm[NHI];
      #pragma unroll
      for (int k = 0; k < NHI; k++) segm[k] = -1e30f;
      #pragma unroll
      for (int m = 0; m < NM; m++) segm[M2H[m]] = fmaxf(segm[M2H[m]], pBx[m]);
      float pCx[NHI];
      #pragma unroll
      for (int k = 0; k < NHI; k++) pCx[k] = fmaxf(segm[k], x[NF + NM + k]);

      float prA = 1.f, prB = 1.f, prM = 1.f, prH = 1.f;
      #pragma unroll
      for (int f = 0; f < NF; f++) {
        const float mx  = fminf(x[f], x[NF + F2M[f]]);
        const float arg = (f == lf) ? -mx : x[f];
        const float t = __builtin_fmaf(vm, __expf(arg), 1.f);
        if (f < 10) prA *= t; else prB *= t;
        sPixF[f * CST + tid] = valid ? mx : -1e30f;
      }
      #pragma unroll
      for (int m = 0; m < NM; m++) {
        const float mx  = fminf(x[NF + m], x[NF + NM + M2H[m]]);
        const float arg = (m == lm) ? -mx : pBx[m];
        prM *= __builtin_fmaf(vm, __expf(arg), 1.f);
        sPixF[(NF + m) * CST + tid] = valid ? mx : -1e30f;
      }
      #pragma unroll
      for (int k = 0; k < NHI; k++) {
        const float px  = x[NF + NM + k];
        const float arg = (k == lh) ? -px : pCx[k];
        prH *= __builtin_fmaf(vm, __expf(arg), 1.f);
        sPixF[(NF + NM + k) * CST + tid] = valid ? px : -1e30f;
      }
      bce0 = __logf(prA) + __logf(prB);
      bce1 = __logf(prM);
      bce2 = __logf(prH);
      sMask[tid] = valid ? ((1u << lf) | (1u << (19 + lm)) | (1u << (26 + lh))) : 0u;
      cnt = vm;
    }
  }

  #pragma unroll
  for (int m = 32; m >= 1; m >>= 1) {
    bce0 += __shfl_xor(bce0, m);
    bce1 += __shfl_xor(bce1, m);
    bce2 += __shfl_xor(bce2, m);
    cnt  += __shfl_xor(cnt, m);
  }
  {
    const int wave = tid >> 6, lane = tid & 63;
    if (lane == 0) {
      sRed[0][wave] = bce0; sRed[1][wave] = bce1;
      sRed[2][wave] = bce2; sRed[3][wave] = cnt;
    }
  }
  __syncthreads();

  if (wy < 170) {
    float* laB = ws + WS_LA;
    float* prB = ws + WS_PR;
    for (int t = tid; t < 464; t += 192) {
      const int c = t >> 4, w = t & 15;
      const int c0 = 3 * w;
      unsigned m = 0u;
      #pragma unroll
      for (int r = 0; r < 3; r++)
        m |= sMask[r * NCOL + c0] | sMask[r * NCOL + c0 + 1] |
             sMask[r * NCOL + c0 + 2];
      float v = -1e30f;
      #pragma unroll
      for (int r = 0; r < 3; r++)
        v = fmaxf(v, fmaxf(fmaxf(sPixF[c * CST + r * NCOL + c0],
                                 sPixF[c * CST + r * NCOL + c0 + 1]),
                           sPixF[c * CST + r * NCOL + c0 + 2]));
      // plane-major store: [bc][wy][16bx + w]  (bx=10, w>=10 -> pad cols, unread)
      const size_t addr = ((size_t)(b * NCHT + c) * PH + wy) * RSTR + 16 * bx + w;
      laB[addr] = (float)((m >> c) & 1u);
      prB[addr] = __builtin_amdgcn_rcpf(1.f + __expf(-v)) + 1e-6f;
    }
  }

  if (tid == 0) {
    const int slot = (bx + 11 * (wy + 171 * b)) & 63;
    float* dst = ws + WS_RED + slot * 16;
    atomicAdd(&dst[0], sRed[0][0] + sRed[0][1] + sRed[0][2]);
    atomicAdd(&dst[1], sRed[1][0] + sRed[1][1] + sRed[1][2]);
    atomicAdd(&dst[2], sRed[2][0] + sRed[2][1] + sRed[2][2]);
    atomicAdd(&dst[3], sRed[3][0] + sRed[3][1] + sRed[3][2]);
  }
}

__global__ __launch_bounds__(192)
void kA(const float* __restrict__ cls, const int* __restrict__ label,
        float* __restrict__ ws) {
  __shared__ __align__(16) float sPixF[NCHT * 144];
  __shared__ unsigned sMask[144];
  __shared__ float    sRed[4][3];
  const int bx = blockIdx.x, wy = blockIdx.y, b = blockIdx.z;
  if (bx < 10)
    kA_body<12>(bx, wy, b, threadIdx.x, cls, label, ws, sPixF, sMask, sRed);
  else
    kA_body<8>(bx, wy, b, threadIdx.x, cls, label, ws, sPixF, sMask, sRed);
}

// ---------------- kernel Cov: sample-per-lane sliding window, no LDS --------
// R17: R16's cost was compute (VALUBusy 40% = 48us: half-width FMA + selects
// + 12 scalar LDS reads/sample). New: lane = sample; 9 views per plane from 3
// rolling row-regs + shfl_down (2 loads + 4 shfl per row-step); wave-uniform
// half splits 171 upper entries (93/78 accs). Reads: 256B coalesced, L3-res.
// grid (116 bc, 7 chunks), 256 thr = 4 waves = 2 halves x 2 rowgroups(12 rows).
__global__ __launch_bounds__(256, 2)
void kCov(const float* __restrict__ ws_base, float* __restrict__ cov,
          float* __restrict__ s1out) {
  const int bc    = blockIdx.x;
  const int chunk = blockIdx.y;
  const int tid   = threadIdx.x;
  const int lane  = tid & 63;
  const int half  = (tid >> 6) & 1;
  const int rg    = tid >> 7;
  const int rbase = chunk * 24 + rg * 12;

  const float* laP = ws_base + WS_LA + (size_t)bc * PH * RSTR;
  const float* prP = ws_base + WS_PR + (size_t)bc * PH * RSTR;

  float acc[93];
  float sums[9];
  #pragma unroll
  for (int k = 0; k < 93; k++) acc[k] = 0.f;
  #pragma unroll
  for (int k = 0; k < 9; k++) sums[k] = 0.f;

  for (int cb = 0; cb < 3; cb++) {
    const int sx  = 62 * cb + lane;
    const int sxc = (sx < 169) ? sx : 169;
    const float okf = (lane < 62 && sx < NHW) ? 1.f : 0.f;
    const float* lc0 = laP + sxc;
    const float* pc0 = prP + sxc;

    float A[9], P[9];
    {
      float x = lc0[(size_t)(rbase + 0) * RSTR];
      A[0] = x; A[1] = __shfl_down(x, 1); A[2] = __shfl_down(x, 2);
      x = lc0[(size_t)(rbase + 1) * RSTR];
      A[3] = x; A[4] = __shfl_down(x, 1); A[5] = __shfl_down(x, 2);
      x = pc0[(size_t)(rbase + 0) * RSTR];
      P[0] = x; P[1] = __shfl_down(x, 1); P[2] = __shfl_down(x, 2);
      x = pc0[(size_t)(rbase + 1) * RSTR];
      P[3] = x; P[4] = __shfl_down(x, 1); P[5] = __shfl_down(x, 2);
    }
    #pragma unroll
    for (int ii = 0; ii < 12; ii++) {
      const int r = rbase + ii;
      {
        float x = lc0[(size_t)(r + 2) * RSTR];
        A[6] = x; A[7] = __shfl_down(x, 1); A[8] = __shfl_down(x, 2);
        x = pc0[(size_t)(r + 2) * RSTR];
        P[6] = x; P[7] = __shfl_down(x, 1); P[8] = __shfl_down(x, 2);
      }
      float vm[18];
      #pragma unroll
      for (int k = 0; k < 9; k++) vm[k] = A[k] * okf;
      #pragma unroll
      for (int k = 0; k < 9; k++) vm[9 + k] = P[k] * okf;

      if (half == 0) {
        int q = 0;
        #pragma unroll
        for (int i = 0; i < 6; i++)
          #pragma unroll
          for (int j = i; j < 6; j++) { acc[q] = fmaf(vm[i], vm[j], acc[q]); q++; }
        #pragma unroll
        for (int i = 0; i < 6; i++)
          #pragma unroll
          for (int j = 0; j < 6; j++) { acc[q] = fmaf(vm[i], vm[6 + j], acc[q]); q++; }
        #pragma unroll
        for (int i = 0; i < 6; i++)
          #pragma unroll
          for (int j = 0; j < 6; j++) { acc[q] = fmaf(vm[i], vm[12 + j], acc[q]); q++; }
        #pragma unroll
        for (int k = 0; k < 9; k++) sums[k] += vm[k];
      } else {
        int q = 0;
        #pragma unroll
        for (int i = 0; i < 6; i++)
          #pragma unroll
          for (int j = i; j < 6; j++) { acc[q] = fmaf(vm[6 + i], vm[6 + j], acc[q]); q++; }
        #pragma unroll
        for (int i = 0; i < 6; i++)
          #pragma unroll
          for (int j = 0; j < 6; j++) { acc[q] = fmaf(vm[6 + i], vm[12 + j], acc[q]); q++; }
        #pragma unroll
        for (int i = 0; i < 6; i++)
          #pragma unroll
          for (int j = i; j < 6; j++) { acc[q] = fmaf(vm[12 + i], vm[12 + j], acc[q]); q++; }
        #pragma unroll
        for (int k = 0; k < 9; k++) sums[k] += vm[9 + k];
      }
      #pragma unroll
      for (int k = 0; k < 6; k++) { A[k] = A[k + 3]; P[k] = P[k + 3]; }
    }
  }

  // wave-reduce + atomics (lane0)
  #pragma unroll
  for (int k = 0; k < 93; k++) {
    float v = acc[k];
    #pragma unroll
    for (int m = 32; m >= 1; m >>= 1) v += __shfl_xor(v, m);
    acc[k] = v;
  }
  #pragma unroll
  for (int k = 0; k < 9; k++) {
    float v = sums[k];
    #pragma unroll
    for (int m = 32; m >= 1; m >>= 1) v += __shfl_xor(v, m);
    sums[k] = v;
  }

  if (lane == 0) {
    float* dst = cov + (size_t)bc * 324;
    if (half == 0) {
      int q = 0;
      #pragma unroll
      for (int i = 0; i < 6; i++)
        #pragma unroll
        for (int j = i; j < 6; j++) { atomicAdd(&dst[i * 18 + j], acc[q]); q++; }
      #pragma unroll
      for (int i = 0; i < 6; i++)
        #pragma unroll
        for (int j = 0; j < 6; j++) { atomicAdd(&dst[i * 18 + 6 + j], acc[q]); q++; }
      #pragma unroll
      for (int i = 0; i < 6; i++)
        #pragma unroll
        for (int j = 0; j < 6; j++) { atomicAdd(&dst[i * 18 + 12 + j], acc[q]); q++; }
      #pragma unroll
      for (int k = 0; k < 9; k++) atomicAdd(&s1out[bc * 32 + k], sums[k]);
    } else {
      int q = 0;
      #pragma unroll
      for (int i = 0; i < 6; i++)
        #pragma unroll
        for (int j = i; j < 6; j++) { atomicAdd(&dst[(6 + i) * 18 + 6 + j], acc[q]); q++; }
      #pragma unroll
      for (int i = 0; i < 6; i++)
        #pragma unroll
        for (int j = 0; j < 6; j++) { atomicAdd(&dst[(6 + i) * 18 + 12 + j], acc[q]); q++; }
      #pragma unroll
      for (int i = 0; i < 6; i++)
        #pragma unroll
        for (int j = i; j < 6; j++) { atomicAdd(&dst[(12 + i) * 18 + 12 + j], acc[q]); q++; }
      #pragma unroll
      for (int k = 0; k < 9; k++) atomicAdd(&s1out[bc * 32 + 9 + k], sums[k]);
    }
  }
}

// ---------------- kernel Solve: one wave per (b,c); center in DOUBLE --------
__global__ __launch_bounds__(64)
void kSolve(const float* __restrict__ cov_all, const float* __restrict__ s1,
            float* __restrict__ acc) {
  const int bc   = blockIdx.x;
  const int lane = threadIdx.x;
  const float* cr = cov_all + (size_t)bc * 324;
  const double n = (double)NS;

  double mu[18];
  #pragma unroll
  for (int r = 0; r < 18; r++) mu[r] = (double)s1[bc * 32 + r] / n;
#define CC(i, j) ((double)cr[(i) * 18 + (j)] - n * mu[(i)] * mu[(j)])

  double row[9];
  #pragma unroll
  for (int j = 0; j < 9; j++)
    row[j] = (lane < 9 && j <= lane) ? CC(9 + j, 9 + lane) : 0.0;
  if (lane < 9) row[lane] += 1e-3;

  #pragma unroll
  for (int k = 0; k < 9; k++) {
    if (lane == k) {
      double s = row[k];
      #pragma unroll
      for (int m = 0; m < k; m++) s -= row[m] * row[m];
      row[k] = sqrt(fmax(s, 1e-300));
    }
    double rk[9];
    #pragma unroll
    for (int m = 0; m <= k; m++) rk[m] = __shfl(row[m], k);
    if (lane > k && lane < 9) {
      double s = row[k];
      #pragma unroll
      for (int m = 0; m < k; m++) s -= row[m] * rk[m];
      row[k] = s / rk[k];
    }
  }

  double Lm[9][9];
  #pragma unroll
  for (int i = 0; i < 9; i++)
    #pragma unroll
    for (int m = 0; m <= i; m++) Lm[i][m] = __shfl(row[m], i);

  double mc[9];
  #pragma unroll
  for (int r = 0; r < 9; r++) mc[r] = 0.0;
  if (lane < 9) {
    #pragma unroll
    for (int r = 0; r < 9; r++) {
      double s = CC(lane, 9 + r);
      #pragma unroll
      for (int m = 0; m < r; m++) s -= Lm[r][m] * mc[m];
      mc[r] = s / Lm[r][r];
    }
  }

  double a2[9];
  #pragma unroll
  for (int j = 0; j < 9; j++) a2[j] = 0.0;
  #pragma unroll
  for (int j = 0; j < 9; j++) {
    double mj[9];
    #pragma unroll
    for (int r = 0; r < 9; r++) mj[r] = __shfl(mc[r], j);
    double dot = 0.0;
    #pragma unroll
    for (int r = 0; r < 9; r++) dot += mc[r] * mj[r];
    if (lane < 9 && j <= lane)
      a2[j] = CC(j, lane) - dot + ((j == lane) ? 1e-3 : 0.0);
  }
#undef CC

  double myld = 0.0;
  #pragma unroll
  for (int k = 0; k < 9; k++) {
    if (lane == k) {
      double s = a2[k];
      #pragma unroll
      for (int m = 0; m < k; m++) s -= a2[m] * a2[m];
      double d = sqrt(fmax(s, 0.0));
      a2[k] = d;
      myld = 2.0 * log(d + 1e-8);
    }
    double rk[9];
    #pragma unroll
    for (int m = 0; m <= k; m++) rk[m] = __shfl(a2[m], k);
    if (lane > k && lane < 9) {
      double s = a2[k];
      #pragma unroll
      for (int m = 0; m < k; m++) s -= a2[m] * rk[m];
      a2[k] = s / rk[k];
    }
  }
  #pragma unroll
  for (int m = 32; m >= 1; m >>= 1) myld += __shfl_xor(myld, m);
  if (lane == 0) atomicAdd(&acc[4], (float)myld);
}

// ---------------- finalize: reduce 64 BCE slots + combine --------------------
__global__ void kFin(const float* __restrict__ ws, float* __restrict__ out) {
  const int tid = threadIdx.x;
  const float* slot = ws + WS_RED + tid * 16;
  float b0 = slot[0], b1 = slot[1], b2 = slot[2], b3 = slot[3];
  #pragma unroll
  for (int m = 32; m >= 1; m >>= 1) {
    b0 += __shfl_xor(b0, m);
    b1 += __shfl_xor(b1, m);
    b2 += __shfl_xor(b2, m);
    b3 += __shfl_xor(b3, m);
  }
  if (tid == 0) {
    const double cnt = (double)b3;
    const double bce = 0.5 * ((double)b0 / (cnt * NF + 1e-8) +
                              (double)b1 / (cnt * NM + 1e-8) +
                              (double)b2 / (cnt * NHI + 1e-8));
    const double rmi = 0.5 * (double)ws[4] / (double)(NB * 9);
    out[0] = (float)(bce + rmi);
  }
}

extern "C" void kernel_launch(void* const* d_in, const int* in_sizes, int n_in,
                              void* d_out, int out_size, void* d_ws, size_t ws_size,
                              hipStream_t stream) {
  (void)in_sizes; (void)n_in; (void)out_size; (void)ws_size;
  const float* cls   = (const float*)d_in[3];
  const int*   label = (const int*)d_in[4];
  float* ws = (float*)d_ws;

  hipMemsetAsync(d_ws, 0, WS_ZERO_BYTES, stream);

  dim3 gA(11, 171, NB);
  kA<<<gA, 192, 0, stream>>>(cls, label, ws);
  kCov<<<dim3(NBC, CCH), 256, 0, stream>>>(ws, ws + WS_COV, ws + WS_S1);
  kSolve<<<NBC, 64, 0, stream>>>(ws + WS_COV, ws + WS_S1, ws);
  kFin<<<1, 64, 0, stream>>>(ws, (float*)d_out);
}

// Round 18
// 148.974 us; speedup vs baseline: 2.4381x; 2.4381x over previous
//
#include <hip/hip_runtime.h>
#include <math.h>

namespace {
constexpr int NB = 4, NCHT = 29, NF = 19, NM = 7, NHI = 3;
constexpr int HH = 512, WW = 512;
constexpr int PH  = 170;           // pooled H/W
constexpr int NHW = 168;           // shifted-view grid
constexpr int NS  = NHW * NHW;     // 28224 samples
constexpr int NBC = NB * NCHT;     // 116
constexpr int RSTR = 176;          // padded plane row stride
constexpr int CCH  = 7;            // kCov chunks (24 rows each)

constexpr int F2M[NF] = {0,0,0,1,1,1,2,2,3,3,4,5,5,6,6,6,6,6,6};
constexpr int M2H[NM] = {0,0,1,1,1,2,2};

constexpr unsigned long long packTbl(const int* a, int n) {
  unsigned long long p = 0;
  for (int i = 0; i < n; i++) p |= (unsigned long long)(a[i]) << (3 * i);
  return p;
}
constexpr int F2H_[NF] = {0,0,0,0,0,0,1,1,1,1,1,2,2,2,2,2,2,2,2};
constexpr unsigned long long PF2M = packTbl(F2M, NF);
constexpr unsigned long long PF2H = packTbl(F2H_, NF);

// ws float layout
constexpr int    WS_S1  = 16;       // raw view sums, 116*32
constexpr int    WS_COV = 4096;     // raw upper-tri moments, 116*324
constexpr int    WS_RED = 49152;    // 64 slots * 16 floats
constexpr size_t PLANER = (size_t)NBC * PH * RSTR;   // 3,470,720 floats
constexpr size_t WS_LA  = 65536;
constexpr size_t WS_PR  = WS_LA + PLANER;
constexpr size_t WS_ZERO_BYTES = (size_t)(WS_RED + 64 * 16) * 4;
} // namespace

// async global->LDS DMA, 16B per lane; LDS dest linear in lane order,
// GLOBAL source per-lane (m104).
#define GLOAD16(gsrc, ldst)                                                     \
  __builtin_amdgcn_global_load_lds(                                             \
      (const __attribute__((address_space(1))) void*)(gsrc),                    \
      (__attribute__((address_space(3))) void*)(ldst), 16, 0, 0)

// ---------------- kernel A: logit-space hierarchy + BCE + pool ---------------
// grid (11, 171, NB), 192 thr. R14 compute; plane-major [bc][wy][wx] stores.
template <int W4>
__device__ __forceinline__ void kA_body(
    const int bx, const int wy, const int b, const int tid,
    const float* __restrict__ cls, const int* __restrict__ label,
    float* __restrict__ ws, float* sPixF, unsigned* sMask, float (*sRed)[3]) {
  constexpr int NCOL = 4 * W4;       // 48 or 32
  constexpr int CST  = 3 * NCOL;     // 144 or 96
  constexpr int T3   = 3 * W4;
  const int x0   = 48 * bx;
  const int y0   = 3 * wy;
  const int rmax = (wy == 170) ? 1 : 2;

  for (int i = tid; i < NCHT * T3; i += 192) {
    const int c   = i / T3;
    const int rem = i - c * T3;
    const int r   = rem / W4;
    const int f   = rem - r * W4;
    const int rr  = (r <= rmax) ? r : rmax;
    const float* src =
        cls + ((size_t)(b * NCHT + c) * HH + (y0 + rr)) * WW + x0 + 4 * f;
    GLOAD16(src, &sPixF[4 * i]);
  }
  __syncthreads();

  float bce0 = 0.f, bce1 = 0.f, bce2 = 0.f, cnt = 0.f;
  if (tid < CST) {
    const int r = tid / NCOL;
    if (r <= rmax) {
      const int col = tid - r * NCOL;
      const int lbl = label[((size_t)b * HH + (y0 + r)) * WW + x0 + col];
      const bool valid = (lbl != 255);
      const int lf = valid ? lbl : 0;
      const int lm = (int)((PF2M >> (3 * lf)) & 7ull);
      const int lh = (int)((PF2H >> (3 * lf)) & 7ull);
      const float vm = valid ? 1.f : 0.f;

      float x[NCHT];
      #pragma unroll
      for (int c = 0; c < NCHT; c++) x[c] = sPixF[c * CST + tid];

      float segf[NM];
      #pragma unroll
      for (int m = 0; m < NM; m++) segf[m] = -1e30f;
      #pragma unroll
      for (int f = 0; f < NF; f++) segf[F2M[f]] = fmaxf(segf[F2M[f]], x[f]);
      float pBx[NM];
      #pragma unroll
      for (int m = 0; m < NM; m++) pBx[m] = fmaxf(segf[m], x[NF + m]);
      float segm[NHI];
      #pragma unroll
      for (int k = 0; k < NHI; k++) segm[k] = -1e30f;
      #pragma unroll
      for (int m = 0; m < NM; m++) segm[M2H[m]] = fmaxf(segm[M2H[m]], pBx[m]);
      float pCx[NHI];
      #pragma unroll
      for (int k = 0; k < NHI; k++) pCx[k] = fmaxf(segm[k], x[NF + NM + k]);

      float prA = 1.f, prB = 1.f, prM = 1.f, prH = 1.f;
      #pragma unroll
      for (int f = 0; f < NF; f++) {
        const float mx  = fminf(x[f], x[NF + F2M[f]]);
        const float arg = (f == lf) ? -mx : x[f];
        const float t = __builtin_fmaf(vm, __expf(arg), 1.f);
        if (f < 10) prA *= t; else prB *= t;
        sPixF[f * CST + tid] = valid ? mx : -1e30f;
      }
      #pragma unroll
      for (int m = 0; m < NM; m++) {
        const float mx  = fminf(x[NF + m], x[NF + NM + M2H[m]]);
        const float arg = (m == lm) ? -mx : pBx[m];
        prM *= __builtin_fmaf(vm, __expf(arg), 1.f);
        sPixF[(NF + m) * CST + tid] = valid ? mx : -1e30f;
      }
      #pragma unroll
      for (int k = 0; k < NHI; k++) {
        const float px  = x[NF + NM + k];
        const float arg = (k == lh) ? -px : pCx[k];
        prH *= __builtin_fmaf(vm, __expf(arg), 1.f);
        sPixF[(NF + NM + k) * CST + tid] = valid ? px : -1e30f;
      }
      bce0 = __logf(prA) + __logf(prB);
      bce1 = __logf(prM);
      bce2 = __logf(prH);
      sMask[tid] = valid ? ((1u << lf) | (1u << (19 + lm)) | (1u << (26 + lh))) : 0u;
      cnt = vm;
    }
  }

  #pragma unroll
  for (int m = 32; m >= 1; m >>= 1) {
    bce0 += __shfl_xor(bce0, m);
    bce1 += __shfl_xor(bce1, m);
    bce2 += __shfl_xor(bce2, m);
    cnt  += __shfl_xor(cnt, m);
  }
  {
    const int wave = tid >> 6, lane = tid & 63;
    if (lane == 0) {
      sRed[0][wave] = bce0; sRed[1][wave] = bce1;
      sRed[2][wave] = bce2; sRed[3][wave] = cnt;
    }
  }
  __syncthreads();

  if (wy < 170) {
    float* laB = ws + WS_LA;
    float* prB = ws + WS_PR;
    for (int t = tid; t < 464; t += 192) {
      const int c = t >> 4, w = t & 15;
      const int c0 = 3 * w;
      unsigned m = 0u;
      #pragma unroll
      for (int r = 0; r < 3; r++)
        m |= sMask[r * NCOL + c0] | sMask[r * NCOL + c0 + 1] |
             sMask[r * NCOL + c0 + 2];
      float v = -1e30f;
      #pragma unroll
      for (int r = 0; r < 3; r++)
        v = fmaxf(v, fmaxf(fmaxf(sPixF[c * CST + r * NCOL + c0],
                                 sPixF[c * CST + r * NCOL + c0 + 1]),
                           sPixF[c * CST + r * NCOL + c0 + 2]));
      const size_t addr = ((size_t)(b * NCHT + c) * PH + wy) * RSTR + 16 * bx + w;
      laB[addr] = (float)((m >> c) & 1u);
      prB[addr] = __builtin_amdgcn_rcpf(1.f + __expf(-v)) + 1e-6f;
    }
  }

  if (tid == 0) {
    const int slot = (bx + 11 * (wy + 171 * b)) & 63;
    float* dst = ws + WS_RED + slot * 16;
    atomicAdd(&dst[0], sRed[0][0] + sRed[0][1] + sRed[0][2]);
    atomicAdd(&dst[1], sRed[1][0] + sRed[1][1] + sRed[1][2]);
    atomicAdd(&dst[2], sRed[2][0] + sRed[2][1] + sRed[2][2]);
    atomicAdd(&dst[3], sRed[3][0] + sRed[3][1] + sRed[3][2]);
  }
}

__global__ __launch_bounds__(192)
void kA(const float* __restrict__ cls, const int* __restrict__ label,
        float* __restrict__ ws) {
  __shared__ __align__(16) float sPixF[NCHT * 144];
  __shared__ unsigned sMask[144];
  __shared__ float    sRed[4][3];
  const int bx = blockIdx.x, wy = blockIdx.y, b = blockIdx.z;
  if (bx < 10)
    kA_body<12>(bx, wy, b, threadIdx.x, cls, label, ws, sPixF, sMask, sRed);
  else
    kA_body<8>(bx, wy, b, threadIdx.x, cls, label, ws, sPixF, sMask, sRed);
}

// ---------------- kernel Cov: sliding window, 4-role split (no spill) -------
// R18: R17's structure was right but acc[93] spilled (VGPR=128 + 310MB scratch
// writes, VALUBusy 7%). Split the 171 upper-tri entries across 4 wave-roles:
// role0 AA-upper(45)+sumsA, role1 AP rows0-3(36), role2 AP rows4-8(45),
// role3 PP-upper(45)+sumsP. Max live ~80 VGPR -> no spill, full-width FMA.
// 512 thr = 8 waves = 4 roles x 2 rowgroups(12 rows). grid (116, 7).
template <int R>
__device__ __forceinline__ void covRole(
    const float* __restrict__ laP, const float* __restrict__ prP,
    const int rbase, const int lane, float* __restrict__ dst,
    float* __restrict__ s1d) {
  constexpr int NACC = (R == 1) ? 36 : 45;
  constexpr bool needA = (R <= 2);
  constexpr bool needP = (R >= 1);

  float acc[NACC];
  #pragma unroll
  for (int k = 0; k < NACC; k++) acc[k] = 0.f;
  float sums[9];
  #pragma unroll
  for (int k = 0; k < 9; k++) sums[k] = 0.f;

  for (int cb = 0; cb < 3; cb++) {
    const int sx  = 62 * cb + lane;
    const int sxc = (sx < 169) ? sx : 169;
    const float okf = (lane < 62 && sx < NHW) ? 1.f : 0.f;
    const float* lc0 = laP + sxc;
    const float* pc0 = prP + sxc;

    float A[9], P[9];
    if (needA) {
      float x = lc0[(size_t)(rbase + 0) * RSTR];
      A[0] = x * okf; A[1] = __shfl_down(x, 1) * okf; A[2] = __shfl_down(x, 2) * okf;
      x = lc0[(size_t)(rbase + 1) * RSTR];
      A[3] = x * okf; A[4] = __shfl_down(x, 1) * okf; A[5] = __shfl_down(x, 2) * okf;
    }
    if (needP) {
      float x = pc0[(size_t)(rbase + 0) * RSTR];
      P[0] = x * okf; P[1] = __shfl_down(x, 1) * okf; P[2] = __shfl_down(x, 2) * okf;
      x = pc0[(size_t)(rbase + 1) * RSTR];
      P[3] = x * okf; P[4] = __shfl_down(x, 1) * okf; P[5] = __shfl_down(x, 2) * okf;
    }
    #pragma unroll
    for (int ii = 0; ii < 12; ii++) {
      const int r = rbase + ii;
      if (needA) {
        float x = lc0[(size_t)(r + 2) * RSTR];
        A[6] = x * okf; A[7] = __shfl_down(x, 1) * okf; A[8] = __shfl_down(x, 2) * okf;
      }
      if (needP) {
        float x = pc0[(size_t)(r + 2) * RSTR];
        P[6] = x * okf; P[7] = __shfl_down(x, 1) * okf; P[8] = __shfl_down(x, 2) * okf;
      }

      if (R == 0) {
        int q = 0;
        #pragma unroll
        for (int i = 0; i < 9; i++)
          #pragma unroll
          for (int j = i; j < 9; j++) { acc[q] = fmaf(A[i], A[j], acc[q]); q++; }
        #pragma unroll
        for (int k = 0; k < 9; k++) sums[k] += A[k];
      } else if (R == 1) {
        int q = 0;
        #pragma unroll
        for (int i = 0; i < 4; i++)
          #pragma unroll
          for (int j = 0; j < 9; j++) { acc[q] = fmaf(A[i], P[j], acc[q]); q++; }
      } else if (R == 2) {
        int q = 0;
        #pragma unroll
        for (int i = 4; i < 9; i++)
          #pragma unroll
          for (int j = 0; j < 9; j++) { acc[q] = fmaf(A[i], P[j], acc[q]); q++; }
      } else {
        int q = 0;
        #pragma unroll
        for (int i = 0; i < 9; i++)
          #pragma unroll
          for (int j = i; j < 9; j++) { acc[q] = fmaf(P[i], P[j], acc[q]); q++; }
        #pragma unroll
        for (int k = 0; k < 9; k++) sums[k] += P[k];
      }

      if (needA) {
        #pragma unroll
        for (int k = 0; k < 6; k++) A[k] = A[k + 3];
      }
      if (needP) {
        #pragma unroll
        for (int k = 0; k < 6; k++) P[k] = P[k + 3];
      }
    }
  }

  #pragma unroll
  for (int k = 0; k < NACC; k++) {
    float v = acc[k];
    #pragma unroll
    for (int m = 32; m >= 1; m >>= 1) v += __shfl_xor(v, m);
    acc[k] = v;
  }
  if (R == 0 || R == 3) {
    #pragma unroll
    for (int k = 0; k < 9; k++) {
      float v = sums[k];
      #pragma unroll
      for (int m = 32; m >= 1; m >>= 1) v += __shfl_xor(v, m);
      sums[k] = v;
    }
  }

  if (lane == 0) {
    if (R == 0) {
      int q = 0;
      #pragma unroll
      for (int i = 0; i < 9; i++)
        #pragma unroll
        for (int j = i; j < 9; j++) { atomicAdd(&dst[i * 18 + j], acc[q]); q++; }
      #pragma unroll
      for (int k = 0; k < 9; k++) atomicAdd(&s1d[k], sums[k]);
    } else if (R == 1) {
      int q = 0;
      #pragma unroll
      for (int i = 0; i < 4; i++)
        #pragma unroll
        for (int j = 0; j < 9; j++) { atomicAdd(&dst[i * 18 + 9 + j], acc[q]); q++; }
    } else if (R == 2) {
      int q = 0;
      #pragma unroll
      for (int i = 4; i < 9; i++)
        #pragma unroll
        for (int j = 0; j < 9; j++) { atomicAdd(&dst[i * 18 + 9 + j], acc[q]); q++; }
    } else {
      int q = 0;
      #pragma unroll
      for (int i = 0; i < 9; i++)
        #pragma unroll
        for (int j = i; j < 9; j++) { atomicAdd(&dst[(9 + i) * 18 + 9 + j], acc[q]); q++; }
      #pragma unroll
      for (int k = 0; k < 9; k++) atomicAdd(&s1d[9 + k], sums[k]);
    }
  }
}

__global__ __launch_bounds__(512, 2)
void kCov(const float* __restrict__ ws_base, float* __restrict__ cov,
          float* __restrict__ s1out) {
  const int bc    = blockIdx.x;
  const int chunk = blockIdx.y;
  const int tid   = threadIdx.x;
  const int lane  = tid & 63;
  const int role  = (tid >> 6) & 3;
  const int rg    = tid >> 8;          // 0..1
  const int rbase = chunk * 24 + rg * 12;

  const float* laP = ws_base + WS_LA + (size_t)bc * PH * RSTR;
  const float* prP = ws_base + WS_PR + (size_t)bc * PH * RSTR;
  float* dst = cov + (size_t)bc * 324;
  float* s1d = s1out + bc * 32;

  if (role == 0)      covRole<0>(laP, prP, rbase, lane, dst, s1d);
  else if (role == 1) covRole<1>(laP, prP, rbase, lane, dst, s1d);
  else if (role == 2) covRole<2>(laP, prP, rbase, lane, dst, s1d);
  else                covRole<3>(laP, prP, rbase, lane, dst, s1d);
}

// ---------------- kernel Solve: one wave per (b,c); center in DOUBLE --------
__global__ __launch_bounds__(64)
void kSolve(const float* __restrict__ cov_all, const float* __restrict__ s1,
            float* __restrict__ acc) {
  const int bc   = blockIdx.x;
  const int lane = threadIdx.x;
  const float* cr = cov_all + (size_t)bc * 324;
  const double n = (double)NS;

  double mu[18];
  #pragma unroll
  for (int r = 0; r < 18; r++) mu[r] = (double)s1[bc * 32 + r] / n;
#define CC(i, j) ((double)cr[(i) * 18 + (j)] - n * mu[(i)] * mu[(j)])

  double row[9];
  #pragma unroll
  for (int j = 0; j < 9; j++)
    row[j] = (lane < 9 && j <= lane) ? CC(9 + j, 9 + lane) : 0.0;
  if (lane < 9) row[lane] += 1e-3;

  #pragma unroll
  for (int k = 0; k < 9; k++) {
    if (lane == k) {
      double s = row[k];
      #pragma unroll
      for (int m = 0; m < k; m++) s -= row[m] * row[m];
      row[k] = sqrt(fmax(s, 1e-300));
    }
    double rk[9];
    #pragma unroll
    for (int m = 0; m <= k; m++) rk[m] = __shfl(row[m], k);
    if (lane > k && lane < 9) {
      double s = row[k];
      #pragma unroll
      for (int m = 0; m < k; m++) s -= row[m] * rk[m];
      row[k] = s / rk[k];
    }
  }

  double Lm[9][9];
  #pragma unroll
  for (int i = 0; i < 9; i++)
    #pragma unroll
    for (int m = 0; m <= i; m++) Lm[i][m] = __shfl(row[m], i);

  double mc[9];
  #pragma unroll
  for (int r = 0; r < 9; r++) mc[r] = 0.0;
  if (lane < 9) {
    #pragma unroll
    for (int r = 0; r < 9; r++) {
      double s = CC(lane, 9 + r);
      #pragma unroll
      for (int m = 0; m < r; m++) s -= Lm[r][m] * mc[m];
      mc[r] = s / Lm[r][r];
    }
  }

  double a2[9];
  #pragma unroll
  for (int j = 0; j < 9; j++) a2[j] = 0.0;
  #pragma unroll
  for (int j = 0; j < 9; j++) {
    double mj[9];
    #pragma unroll
    for (int r = 0; r < 9; r++) mj[r] = __shfl(mc[r], j);
    double dot = 0.0;
    #pragma unroll
    for (int r = 0; r < 9; r++) dot += mc[r] * mj[r];
    if (lane < 9 && j <= lane)
      a2[j] = CC(j, lane) - dot + ((j == lane) ? 1e-3 : 0.0);
  }
#undef CC

  double myld = 0.0;
  #pragma unroll
  for (int k = 0; k < 9; k++) {
    if (lane == k) {
      double s = a2[k];
      #pragma unroll
      for (int m = 0; m < k; m++) s -= a2[m] * a2[m];
      double d = sqrt(fmax(s, 0.0));
      a2[k] = d;
      myld = 2.0 * log(d + 1e-8);
    }
    double rk[9];
    #pragma unroll
    for (int m = 0; m <= k; m++) rk[m] = __shfl(a2[m], k);
    if (lane > k && lane < 9) {
      double s = a2[k];
      #pragma unroll
      for (int m = 0; m < k; m++) s -= a2[m] * rk[m];
      a2[k] = s / rk[k];
    }
  }
  #pragma unroll
  for (int m = 32; m >= 1; m >>= 1) myld += __shfl_xor(myld, m);
  if (lane == 0) atomicAdd(&acc[4], (float)myld);
}

// ---------------- finalize: reduce 64 BCE slots + combine --------------------
__global__ void kFin(const float* __restrict__ ws, float* __restrict__ out) {
  const int tid = threadIdx.x;
  const float* slot = ws + WS_RED + tid * 16;
  float b0 = slot[0], b1 = slot[1], b2 = slot[2], b3 = slot[3];
  #pragma unroll
  for (int m = 32; m >= 1; m >>= 1) {
    b0 += __shfl_xor(b0, m);
    b1 += __shfl_xor(b1, m);
    b2 += __shfl_xor(b2, m);
    b3 += __shfl_xor(b3, m);
  }
  if (tid == 0) {
    const double cnt = (double)b3;
    const double bce = 0.5 * ((double)b0 / (cnt * NF + 1e-8) +
                              (double)b1 / (cnt * NM + 1e-8) +
                              (double)b2 / (cnt * NHI + 1e-8));
    const double rmi = 0.5 * (double)ws[4] / (double)(NB * 9);
    out[0] = (float)(bce + rmi);
  }
}

extern "C" void kernel_launch(void* const* d_in, const int* in_sizes, int n_in,
                              void* d_out, int out_size, void* d_ws, size_t ws_size,
                              hipStream_t stream) {
  (void)in_sizes; (void)n_in; (void)out_size; (void)ws_size;
  const float* cls   = (const float*)d_in[3];
  const int*   label = (const int*)d_in[4];
  float* ws = (float*)d_ws;

  hipMemsetAsync(d_ws, 0, WS_ZERO_BYTES, stream);

  dim3 gA(11, 171, NB);
  kA<<<gA, 192, 0, stream>>>(cls, label, ws);
  kCov<<<dim3(NBC, CCH), 512, 0, stream>>>(ws, ws + WS_COV, ws + WS_S1);
  kSolve<<<NBC, 64, 0, stream>>>(ws + WS_COV, ws + WS_S1, ws);
  kFin<<<1, 64, 0, stream>>>(ws, (float*)d_out);
}

// Round 19
// 146.188 us; speedup vs baseline: 2.4846x; 1.0191x over previous
//
#include <hip/hip_runtime.h>
#include <math.h>

namespace {
constexpr int NB = 4, NCHT = 29, NF = 19, NM = 7, NHI = 3;
constexpr int HH = 512, WW = 512;
constexpr int PH  = 170;           // pooled H/W
constexpr int NHW = 168;           // shifted-view grid
constexpr int NS  = NHW * NHW;     // 28224 samples
constexpr int NBC = NB * NCHT;     // 116
constexpr int RSTR = 176;          // padded plane row stride
constexpr int CCH  = 14;           // kCov chunks (12 rows each)

constexpr int F2M[NF] = {0,0,0,1,1,1,2,2,3,3,4,5,5,6,6,6,6,6,6};
constexpr int M2H[NM] = {0,0,1,1,1,2,2};

constexpr unsigned long long packTbl(const int* a, int n) {
  unsigned long long p = 0;
  for (int i = 0; i < n; i++) p |= (unsigned long long)(a[i]) << (3 * i);
  return p;
}
constexpr int F2H_[NF] = {0,0,0,0,0,0,1,1,1,1,1,2,2,2,2,2,2,2,2};
constexpr unsigned long long PF2M = packTbl(F2M, NF);
constexpr unsigned long long PF2H = packTbl(F2H_, NF);

// ws float layout
constexpr int    WS_S1  = 16;       // raw view sums, 116*32
constexpr int    WS_COV = 4096;     // raw upper-tri moments, 116*324
constexpr int    WS_RED = 49152;    // 64 slots * 16 floats
constexpr size_t PLANER = (size_t)NBC * PH * RSTR;   // 3,470,720 floats
constexpr size_t WS_LA  = 65536;
constexpr size_t WS_PR  = WS_LA + PLANER;
constexpr size_t WS_ZERO_BYTES = (size_t)(WS_RED + 64 * 16) * 4;
} // namespace

// async global->LDS DMA, 16B per lane; LDS dest linear in lane order,
// GLOBAL source per-lane (m104).
#define GLOAD16(gsrc, ldst)                                                     \
  __builtin_amdgcn_global_load_lds(                                             \
      (const __attribute__((address_space(1))) void*)(gsrc),                    \
      (__attribute__((address_space(3))) void*)(ldst), 16, 0, 0)

// ---------------- kernel A: logit-space hierarchy + BCE + pool ---------------
// grid (11, 171, NB), 192 thr. R14 compute; plane-major [bc][wy][wx] stores.
template <int W4>
__device__ __forceinline__ void kA_body(
    const int bx, const int wy, const int b, const int tid,
    const float* __restrict__ cls, const int* __restrict__ label,
    float* __restrict__ ws, float* sPixF, unsigned* sMask, float (*sRed)[3]) {
  constexpr int NCOL = 4 * W4;       // 48 or 32
  constexpr int CST  = 3 * NCOL;     // 144 or 96
  constexpr int T3   = 3 * W4;
  const int x0   = 48 * bx;
  const int y0   = 3 * wy;
  const int rmax = (wy == 170) ? 1 : 2;

  for (int i = tid; i < NCHT * T3; i += 192) {
    const int c   = i / T3;
    const int rem = i - c * T3;
    const int r   = rem / W4;
    const int f   = rem - r * W4;
    const int rr  = (r <= rmax) ? r : rmax;
    const float* src =
        cls + ((size_t)(b * NCHT + c) * HH + (y0 + rr)) * WW + x0 + 4 * f;
    GLOAD16(src, &sPixF[4 * i]);
  }
  __syncthreads();

  float bce0 = 0.f, bce1 = 0.f, bce2 = 0.f, cnt = 0.f;
  if (tid < CST) {
    const int r = tid / NCOL;
    if (r <= rmax) {
      const int col = tid - r * NCOL;
      const int lbl = label[((size_t)b * HH + (y0 + r)) * WW + x0 + col];
      const bool valid = (lbl != 255);
      const int lf = valid ? lbl : 0;
      const int lm = (int)((PF2M >> (3 * lf)) & 7ull);
      const int lh = (int)((PF2H >> (3 * lf)) & 7ull);
      const float vm = valid ? 1.f : 0.f;

      float x[NCHT];
      #pragma unroll
      for (int c = 0; c < NCHT; c++) x[c] = sPixF[c * CST + tid];

      float segf[NM];
      #pragma unroll
      for (int m = 0; m < NM; m++) segf[m] = -1e30f;
      #pragma unroll
      for (int f = 0; f < NF; f++) segf[F2M[f]] = fmaxf(segf[F2M[f]], x[f]);
      float pBx[NM];
      #pragma unroll
      for (int m = 0; m < NM; m++) pBx[m] = fmaxf(segf[m], x[NF + m]);
      float segm[NHI];
      #pragma unroll
      for (int k = 0; k < NHI; k++) segm[k] = -1e30f;
      #pragma unroll
      for (int m = 0; m < NM; m++) segm[M2H[m]] = fmaxf(segm[M2H[m]], pBx[m]);
      float pCx[NHI];
      #pragma unroll
      for (int k = 0; k < NHI; k++) pCx[k] = fmaxf(segm[k], x[NF + NM + k]);

      float prA = 1.f, prB = 1.f, prM = 1.f, prH = 1.f;
      #pragma unroll
      for (int f = 0; f < NF; f++) {
        const float mx  = fminf(x[f], x[NF + F2M[f]]);
        const float arg = (f == lf) ? -mx : x[f];
        const float t = __builtin_fmaf(vm, __expf(arg), 1.f);
        if (f < 10) prA *= t; else prB *= t;
        sPixF[f * CST + tid] = valid ? mx : -1e30f;
      }
      #pragma unroll
      for (int m = 0; m < NM; m++) {
        const float mx  = fminf(x[NF + m], x[NF + NM + M2H[m]]);
        const float arg = (m == lm) ? -mx : pBx[m];
        prM *= __builtin_fmaf(vm, __expf(arg), 1.f);
        sPixF[(NF + m) * CST + tid] = valid ? mx : -1e30f;
      }
      #pragma unroll
      for (int k = 0; k < NHI; k++) {
        const float px  = x[NF + NM + k];
        const float arg = (k == lh) ? -px : pCx[k];
        prH *= __builtin_fmaf(vm, __expf(arg), 1.f);
        sPixF[(NF + NM + k) * CST + tid] = valid ? px : -1e30f;
      }
      bce0 = __logf(prA) + __logf(prB);
      bce1 = __logf(prM);
      bce2 = __logf(prH);
      sMask[tid] = valid ? ((1u << lf) | (1u << (19 + lm)) | (1u << (26 + lh))) : 0u;
      cnt = vm;
    }
  }

  #pragma unroll
  for (int m = 32; m >= 1; m >>= 1) {
    bce0 += __shfl_xor(bce0, m);
    bce1 += __shfl_xor(bce1, m);
    bce2 += __shfl_xor(bce2, m);
    cnt  += __shfl_xor(cnt, m);
  }
  {
    const int wave = tid >> 6, lane = tid & 63;
    if (lane == 0) {
      sRed[0][wave] = bce0; sRed[1][wave] = bce1;
      sRed[2][wave] = bce2; sRed[3][wave] = cnt;
    }
  }
  __syncthreads();

  if (wy < 170) {
    float* laB = ws + WS_LA;
    float* prB = ws + WS_PR;
    for (int t = tid; t < 464; t += 192) {
      const int c = t >> 4, w = t & 15;
      const int c0 = 3 * w;
      unsigned m = 0u;
      #pragma unroll
      for (int r = 0; r < 3; r++)
        m |= sMask[r * NCOL + c0] | sMask[r * NCOL + c0 + 1] |
             sMask[r * NCOL + c0 + 2];
      float v = -1e30f;
      #pragma unroll
      for (int r = 0; r < 3; r++)
        v = fmaxf(v, fmaxf(fmaxf(sPixF[c * CST + r * NCOL + c0],
                                 sPixF[c * CST + r * NCOL + c0 + 1]),
                           sPixF[c * CST + r * NCOL + c0 + 2]));
      const size_t addr = ((size_t)(b * NCHT + c) * PH + wy) * RSTR + 16 * bx + w;
      laB[addr] = (float)((m >> c) & 1u);
      prB[addr] = __builtin_amdgcn_rcpf(1.f + __expf(-v)) + 1e-6f;
    }
  }

  if (tid == 0) {
    const int slot = (bx + 11 * (wy + 171 * b)) & 63;
    float* dst = ws + WS_RED + slot * 16;
    atomicAdd(&dst[0], sRed[0][0] + sRed[0][1] + sRed[0][2]);
    atomicAdd(&dst[1], sRed[1][0] + sRed[1][1] + sRed[1][2]);
    atomicAdd(&dst[2], sRed[2][0] + sRed[2][1] + sRed[2][2]);
    atomicAdd(&dst[3], sRed[3][0] + sRed[3][1] + sRed[3][2]);
  }
}

__global__ __launch_bounds__(192)
void kA(const float* __restrict__ cls, const int* __restrict__ label,
        float* __restrict__ ws) {
  __shared__ __align__(16) float sPixF[NCHT * 144];
  __shared__ unsigned sMask[144];
  __shared__ float    sRed[4][3];
  const int bx = blockIdx.x, wy = blockIdx.y, b = blockIdx.z;
  if (bx < 10)
    kA_body<12>(bx, wy, b, threadIdx.x, cls, label, ws, sPixF, sMask, sRed);
  else
    kA_body<8>(bx, wy, b, threadIdx.x, cls, label, ws, sPixF, sMask, sRed);
}

// ---------------- kernel Cov: sliding window, 4-role split ------------------
// R19: R18's 84us was an occupancy unit error — __launch_bounds__(512,2) is
// 2 waves/SIMD = ONE 512-thr block/CU (17.5% occ) leaving the per-row-step
// dependent L2 loads uncovered. Now: 256 thr = 4 waves = the 4 roles exactly,
// grid (116,14) 12-row chunks, __launch_bounds__(256,5) -> 5 blocks/CU =
// 20 waves/CU (62% ceiling), VGPR cap ~102 > 72 so no spill.
template <int R>
__device__ __forceinline__ void covRole(
    const float* __restrict__ laP, const float* __restrict__ prP,
    const int rbase, const int lane, float* __restrict__ dst,
    float* __restrict__ s1d) {
  constexpr int NACC = (R == 1) ? 36 : 45;
  constexpr bool needA = (R <= 2);
  constexpr bool needP = (R >= 1);

  float acc[NACC];
  #pragma unroll
  for (int k = 0; k < NACC; k++) acc[k] = 0.f;
  float sums[9];
  #pragma unroll
  for (int k = 0; k < 9; k++) sums[k] = 0.f;

  for (int cb = 0; cb < 3; cb++) {
    const int sx  = 62 * cb + lane;
    const int sxc = (sx < 169) ? sx : 169;
    const float okf = (lane < 62 && sx < NHW) ? 1.f : 0.f;
    const float* lc0 = laP + sxc;
    const float* pc0 = prP + sxc;

    float A[9], P[9];
    if (needA) {
      float x = lc0[(size_t)(rbase + 0) * RSTR];
      A[0] = x * okf; A[1] = __shfl_down(x, 1) * okf; A[2] = __shfl_down(x, 2) * okf;
      x = lc0[(size_t)(rbase + 1) * RSTR];
      A[3] = x * okf; A[4] = __shfl_down(x, 1) * okf; A[5] = __shfl_down(x, 2) * okf;
    }
    if (needP) {
      float x = pc0[(size_t)(rbase + 0) * RSTR];
      P[0] = x * okf; P[1] = __shfl_down(x, 1) * okf; P[2] = __shfl_down(x, 2) * okf;
      x = pc0[(size_t)(rbase + 1) * RSTR];
      P[3] = x * okf; P[4] = __shfl_down(x, 1) * okf; P[5] = __shfl_down(x, 2) * okf;
    }
    #pragma unroll
    for (int ii = 0; ii < 12; ii++) {
      const int r = rbase + ii;
      if (needA) {
        float x = lc0[(size_t)(r + 2) * RSTR];
        A[6] = x * okf; A[7] = __shfl_down(x, 1) * okf; A[8] = __shfl_down(x, 2) * okf;
      }
      if (needP) {
        float x = pc0[(size_t)(r + 2) * RSTR];
        P[6] = x * okf; P[7] = __shfl_down(x, 1) * okf; P[8] = __shfl_down(x, 2) * okf;
      }

      if (R == 0) {
        int q = 0;
        #pragma unroll
        for (int i = 0; i < 9; i++)
          #pragma unroll
          for (int j = i; j < 9; j++) { acc[q] = fmaf(A[i], A[j], acc[q]); q++; }
        #pragma unroll
        for (int k = 0; k < 9; k++) sums[k] += A[k];
      } else if (R == 1) {
        int q = 0;
        #pragma unroll
        for (int i = 0; i < 4; i++)
          #pragma unroll
          for (int j = 0; j < 9; j++) { acc[q] = fmaf(A[i], P[j], acc[q]); q++; }
      } else if (R == 2) {
        int q = 0;
        #pragma unroll
        for (int i = 4; i < 9; i++)
          #pragma unroll
          for (int j = 0; j < 9; j++) { acc[q] = fmaf(A[i], P[j], acc[q]); q++; }
      } else {
        int q = 0;
        #pragma unroll
        for (int i = 0; i < 9; i++)
          #pragma unroll
          for (int j = i; j < 9; j++) { acc[q] = fmaf(P[i], P[j], acc[q]); q++; }
        #pragma unroll
        for (int k = 0; k < 9; k++) sums[k] += P[k];
      }

      if (needA) {
        #pragma unroll
        for (int k = 0; k < 6; k++) A[k] = A[k + 3];
      }
      if (needP) {
        #pragma unroll
        for (int k = 0; k < 6; k++) P[k] = P[k + 3];
      }
    }
  }

  #pragma unroll
  for (int k = 0; k < NACC; k++) {
    float v = acc[k];
    #pragma unroll
    for (int m = 32; m >= 1; m >>= 1) v += __shfl_xor(v, m);
    acc[k] = v;
  }
  if (R == 0 || R == 3) {
    #pragma unroll
    for (int k = 0; k < 9; k++) {
      float v = sums[k];
      #pragma unroll
      for (int m = 32; m >= 1; m >>= 1) v += __shfl_xor(v, m);
      sums[k] = v;
    }
  }

  if (lane == 0) {
    if (R == 0) {
      int q = 0;
      #pragma unroll
      for (int i = 0; i < 9; i++)
        #pragma unroll
        for (int j = i; j < 9; j++) { atomicAdd(&dst[i * 18 + j], acc[q]); q++; }
      #pragma unroll
      for (int k = 0; k < 9; k++) atomicAdd(&s1d[k], sums[k]);
    } else if (R == 1) {
      int q = 0;
      #pragma unroll
      for (int i = 0; i < 4; i++)
        #pragma unroll
        for (int j = 0; j < 9; j++) { atomicAdd(&dst[i * 18 + 9 + j], acc[q]); q++; }
    } else if (R == 2) {
      int q = 0;
      #pragma unroll
      for (int i = 4; i < 9; i++)
        #pragma unroll
        for (int j = 0; j < 9; j++) { atomicAdd(&dst[i * 18 + 9 + j], acc[q]); q++; }
    } else {
      int q = 0;
      #pragma unroll
      for (int i = 0; i < 9; i++)
        #pragma unroll
        for (int j = i; j < 9; j++) { atomicAdd(&dst[(9 + i) * 18 + 9 + j], acc[q]); q++; }
      #pragma unroll
      for (int k = 0; k < 9; k++) atomicAdd(&s1d[9 + k], sums[k]);
    }
  }
}

__global__ __launch_bounds__(256, 5)
void kCov(const float* __restrict__ ws_base, float* __restrict__ cov,
          float* __restrict__ s1out) {
  const int bc    = blockIdx.x;
  const int chunk = blockIdx.y;
  const int tid   = threadIdx.x;
  const int lane  = tid & 63;
  const int role  = tid >> 6;          // 0..3
  const int rbase = chunk * 12;

  const float* laP = ws_base + WS_LA + (size_t)bc * PH * RSTR;
  const float* prP = ws_base + WS_PR + (size_t)bc * PH * RSTR;
  float* dst = cov + (size_t)bc * 324;
  float* s1d = s1out + bc * 32;

  if (role == 0)      covRole<0>(laP, prP, rbase, lane, dst, s1d);
  else if (role == 1) covRole<1>(laP, prP, rbase, lane, dst, s1d);
  else if (role == 2) covRole<2>(laP, prP, rbase, lane, dst, s1d);
  else                covRole<3>(laP, prP, rbase, lane, dst, s1d);
}

// ---------------- kernel Solve: one wave per (b,c); center in DOUBLE --------
__global__ __launch_bounds__(64)
void kSolve(const float* __restrict__ cov_all, const float* __restrict__ s1,
            float* __restrict__ acc) {
  const int bc   = blockIdx.x;
  const int lane = threadIdx.x;
  const float* cr = cov_all + (size_t)bc * 324;
  const double n = (double)NS;

  double mu[18];
  #pragma unroll
  for (int r = 0; r < 18; r++) mu[r] = (double)s1[bc * 32 + r] / n;
#define CC(i, j) ((double)cr[(i) * 18 + (j)] - n * mu[(i)] * mu[(j)])

  double row[9];
  #pragma unroll
  for (int j = 0; j < 9; j++)
    row[j] = (lane < 9 && j <= lane) ? CC(9 + j, 9 + lane) : 0.0;
  if (lane < 9) row[lane] += 1e-3;

  #pragma unroll
  for (int k = 0; k < 9; k++) {
    if (lane == k) {
      double s = row[k];
      #pragma unroll
      for (int m = 0; m < k; m++) s -= row[m] * row[m];
      row[k] = sqrt(fmax(s, 1e-300));
    }
    double rk[9];
    #pragma unroll
    for (int m = 0; m <= k; m++) rk[m] = __shfl(row[m], k);
    if (lane > k && lane < 9) {
      double s = row[k];
      #pragma unroll
      for (int m = 0; m < k; m++) s -= row[m] * rk[m];
      row[k] = s / rk[k];
    }
  }

  double Lm[9][9];
  #pragma unroll
  for (int i = 0; i < 9; i++)
    #pragma unroll
    for (int m = 0; m <= i; m++) Lm[i][m] = __shfl(row[m], i);

  double mc[9];
  #pragma unroll
  for (int r = 0; r < 9; r++) mc[r] = 0.0;
  if (lane < 9) {
    #pragma unroll
    for (int r = 0; r < 9; r++) {
      double s = CC(lane, 9 + r);
      #pragma unroll
      for (int m = 0; m < r; m++) s -= Lm[r][m] * mc[m];
      mc[r] = s / Lm[r][r];
    }
  }

  double a2[9];
  #pragma unroll
  for (int j = 0; j < 9; j++) a2[j] = 0.0;
  #pragma unroll
  for (int j = 0; j < 9; j++) {
    double mj[9];
    #pragma unroll
    for (int r = 0; r < 9; r++) mj[r] = __shfl(mc[r], j);
    double dot = 0.0;
    #pragma unroll
    for (int r = 0; r < 9; r++) dot += mc[r] * mj[r];
    if (lane < 9 && j <= lane)
      a2[j] = CC(j, lane) - dot + ((j == lane) ? 1e-3 : 0.0);
  }
#undef CC

  double myld = 0.0;
  #pragma unroll
  for (int k = 0; k < 9; k++) {
    if (lane == k) {
      double s = a2[k];
      #pragma unroll
      for (int m = 0; m < k; m++) s -= a2[m] * a2[m];
      double d = sqrt(fmax(s, 0.0));
      a2[k] = d;
      myld = 2.0 * log(d + 1e-8);
    }
    double rk[9];
    #pragma unroll
    for (int m = 0; m <= k; m++) rk[m] = __shfl(a2[m], k);
    if (lane > k && lane < 9) {
      double s = a2[k];
      #pragma unroll
      for (int m = 0; m < k; m++) s -= a2[m] * rk[m];
      a2[k] = s / rk[k];
    }
  }
  #pragma unroll
  for (int m = 32; m >= 1; m >>= 1) myld += __shfl_xor(myld, m);
  if (lane == 0) atomicAdd(&acc[4], (float)myld);
}

// ---------------- finalize: reduce 64 BCE slots + combine --------------------
__global__ void kFin(const float* __restrict__ ws, float* __restrict__ out) {
  const int tid = threadIdx.x;
  const float* slot = ws + WS_RED + tid * 16;
  float b0 = slot[0], b1 = slot[1], b2 = slot[2], b3 = slot[3];
  #pragma unroll
  for (int m = 32; m >= 1; m >>= 1) {
    b0 += __shfl_xor(b0, m);
    b1 += __shfl_xor(b1, m);
    b2 += __shfl_xor(b2, m);
    b3 += __shfl_xor(b3, m);
  }
  if (tid == 0) {
    const double cnt = (double)b3;
    const double bce = 0.5 * ((double)b0 / (cnt * NF + 1e-8) +
                              (double)b1 / (cnt * NM + 1e-8) +
                              (double)b2 / (cnt * NHI + 1e-8));
    const double rmi = 0.5 * (double)ws[4] / (double)(NB * 9);
    out[0] = (float)(bce + rmi);
  }
}

extern "C" void kernel_launch(void* const* d_in, const int* in_sizes, int n_in,
                              void* d_out, int out_size, void* d_ws, size_t ws_size,
                              hipStream_t stream) {
  (void)in_sizes; (void)n_in; (void)out_size; (void)ws_size;
  const float* cls   = (const float*)d_in[3];
  const int*   label = (const int*)d_in[4];
  float* ws = (float*)d_ws;

  hipMemsetAsync(d_ws, 0, WS_ZERO_BYTES, stream);

  dim3 gA(11, 171, NB);
  kA<<<gA, 192, 0, stream>>>(cls, label, ws);
  kCov<<<dim3(NBC, CCH), 256, 0, stream>>>(ws, ws + WS_COV, ws + WS_S1);
  kSolve<<<NBC, 64, 0, stream>>>(ws + WS_COV, ws + WS_S1, ws);
  kFin<<<1, 64, 0, stream>>>(ws, (float*)d_out);
}

// Round 20
// 130.448 us; speedup vs baseline: 2.7844x; 1.1207x over previous
//
#include <hip/hip_runtime.h>
#include <math.h>

namespace {
constexpr int NB = 4, NCHT = 29, NF = 19, NM = 7, NHI = 3;
constexpr int HH = 512, WW = 512;
constexpr int PH  = 170;           // pooled H/W
constexpr int NHW = 168;           // shifted-view grid
constexpr int NS  = NHW * NHW;     // 28224 samples
constexpr int NBC = NB * NCHT;     // 116
constexpr int RSTR = 176;          // padded plane row stride
constexpr int CCH  = 14;           // kCov chunks (12 rows each)
constexpr int PSTR = 192;          // partials stride per (bc,chunk)

constexpr int F2M[NF] = {0,0,0,1,1,1,2,2,3,3,4,5,5,6,6,6,6,6,6};
constexpr int M2H[NM] = {0,0,1,1,1,2,2};

constexpr unsigned long long packTbl(const int* a, int n) {
  unsigned long long p = 0;
  for (int i = 0; i < n; i++) p |= (unsigned long long)(a[i]) << (3 * i);
  return p;
}
constexpr int F2H_[NF] = {0,0,0,0,0,0,1,1,1,1,1,2,2,2,2,2,2,2,2};
constexpr unsigned long long PF2M = packTbl(F2M, NF);
constexpr unsigned long long PF2H = packTbl(F2H_, NF);

// ws float layout
constexpr int    WS_S1  = 16;       // view sums, 116*32 (written by kRed)
constexpr int    WS_COV = 4096;     // upper-tri moments, 116*324 (by kRed)
constexpr int    WS_RED = 49152;    // 64 slots * 16 floats (BCE partials)
constexpr size_t PLANER = (size_t)NBC * PH * RSTR;   // 3,470,720 floats
constexpr size_t WS_LA  = 65536;
constexpr size_t WS_PR  = WS_LA + PLANER;
constexpr size_t WS_PART = WS_PR + PLANER;           // 116*14*192 floats
constexpr size_t WS_ZERO_BYTES = (size_t)(WS_RED + 64 * 16) * 4;
} // namespace

// async global->LDS DMA, 16B per lane; LDS dest linear in lane order,
// GLOBAL source per-lane (m104).
#define GLOAD16(gsrc, ldst)                                                     \
  __builtin_amdgcn_global_load_lds(                                             \
      (const __attribute__((address_space(1))) void*)(gsrc),                    \
      (__attribute__((address_space(3))) void*)(ldst), 16, 0, 0)

// ---------------- kernel A: logit-space hierarchy + BCE + pool ---------------
// grid (11, 171, NB), 192 thr. R14 compute; plane-major [bc][wy][wx] stores.
template <int W4>
__device__ __forceinline__ void kA_body(
    const int bx, const int wy, const int b, const int tid,
    const float* __restrict__ cls, const int* __restrict__ label,
    float* __restrict__ ws, float* sPixF, unsigned* sMask, float (*sRed)[3]) {
  constexpr int NCOL = 4 * W4;       // 48 or 32
  constexpr int CST  = 3 * NCOL;     // 144 or 96
  constexpr int T3   = 3 * W4;
  const int x0   = 48 * bx;
  const int y0   = 3 * wy;
  const int rmax = (wy == 170) ? 1 : 2;

  for (int i = tid; i < NCHT * T3; i += 192) {
    const int c   = i / T3;
    const int rem = i - c * T3;
    const int r   = rem / W4;
    const int f   = rem - r * W4;
    const int rr  = (r <= rmax) ? r : rmax;
    const float* src =
        cls + ((size_t)(b * NCHT + c) * HH + (y0 + rr)) * WW + x0 + 4 * f;
    GLOAD16(src, &sPixF[4 * i]);
  }
  __syncthreads();

  float bce0 = 0.f, bce1 = 0.f, bce2 = 0.f, cnt = 0.f;
  if (tid < CST) {
    const int r = tid / NCOL;
    if (r <= rmax) {
      const int col = tid - r * NCOL;
      const int lbl = label[((size_t)b * HH + (y0 + r)) * WW + x0 + col];
      const bool valid = (lbl != 255);
      const int lf = valid ? lbl : 0;
      const int lm = (int)((PF2M >> (3 * lf)) & 7ull);
      const int lh = (int)((PF2H >> (3 * lf)) & 7ull);
      const float vm = valid ? 1.f : 0.f;

      float x[NCHT];
      #pragma unroll
      for (int c = 0; c < NCHT; c++) x[c] = sPixF[c * CST + tid];

      float segf[NM];
      #pragma unroll
      for (int m = 0; m < NM; m++) segf[m] = -1e30f;
      #pragma unroll
      for (int f = 0; f < NF; f++) segf[F2M[f]] = fmaxf(segf[F2M[f]], x[f]);
      float pBx[NM];
      #pragma unroll
      for (int m = 0; m < NM; m++) pBx[m] = fmaxf(segf[m], x[NF + m]);
      float segm[NHI];
      #pragma unroll
      for (int k = 0; k < NHI; k++) segm[k] = -1e30f;
      #pragma unroll
      for (int m = 0; m < NM; m++) segm[M2H[m]] = fmaxf(segm[M2H[m]], pBx[m]);
      float pCx[NHI];
      #pragma unroll
      for (int k = 0; k < NHI; k++) pCx[k] = fmaxf(segm[k], x[NF + NM + k]);

      float prA = 1.f, prB = 1.f, prM = 1.f, prH = 1.f;
      #pragma unroll
      for (int f = 0; f < NF; f++) {
        const float mx  = fminf(x[f], x[NF + F2M[f]]);
        const float arg = (f == lf) ? -mx : x[f];
        const float t = __builtin_fmaf(vm, __expf(arg), 1.f);
        if (f < 10) prA *= t; else prB *= t;
        sPixF[f * CST + tid] = valid ? mx : -1e30f;
      }
      #pragma unroll
      for (int m = 0; m < NM; m++) {
        const float mx  = fminf(x[NF + m], x[NF + NM + M2H[m]]);
        const float arg = (m == lm) ? -mx : pBx[m];
        prM *= __builtin_fmaf(vm, __expf(arg), 1.f);
        sPixF[(NF + m) * CST + tid] = valid ? mx : -1e30f;
      }
      #pragma unroll
      for (int k = 0; k < NHI; k++) {
        const float px  = x[NF + NM + k];
        const float arg = (k == lh) ? -px : pCx[k];
        prH *= __builtin_fmaf(vm, __expf(arg), 1.f);
        sPixF[(NF + NM + k) * CST + tid] = valid ? px : -1e30f;
      }
      bce0 = __logf(prA) + __logf(prB);
      bce1 = __logf(prM);
      bce2 = __logf(prH);
      sMask[tid] = valid ? ((1u << lf) | (1u << (19 + lm)) | (1u << (26 + lh))) : 0u;
      cnt = vm;
    }
  }

  #pragma unroll
  for (int m = 32; m >= 1; m >>= 1) {
    bce0 += __shfl_xor(bce0, m);
    bce1 += __shfl_xor(bce1, m);
    bce2 += __shfl_xor(bce2, m);
    cnt  += __shfl_xor(cnt, m);
  }
  {
    const int wave = tid >> 6, lane = tid & 63;
    if (lane == 0) {
      sRed[0][wave] = bce0; sRed[1][wave] = bce1;
      sRed[2][wave] = bce2; sRed[3][wave] = cnt;
    }
  }
  __syncthreads();

  if (wy < 170) {
    float* laB = ws + WS_LA;
    float* prB = ws + WS_PR;
    for (int t = tid; t < 464; t += 192) {
      const int c = t >> 4, w = t & 15;
      const int c0 = 3 * w;
      unsigned m = 0u;
      #pragma unroll
      for (int r = 0; r < 3; r++)
        m |= sMask[r * NCOL + c0] | sMask[r * NCOL + c0 + 1] |
             sMask[r * NCOL + c0 + 2];
      float v = -1e30f;
      #pragma unroll
      for (int r = 0; r < 3; r++)
        v = fmaxf(v, fmaxf(fmaxf(sPixF[c * CST + r * NCOL + c0],
                                 sPixF[c * CST + r * NCOL + c0 + 1]),
                           sPixF[c * CST + r * NCOL + c0 + 2]));
      const size_t addr = ((size_t)(b * NCHT + c) * PH + wy) * RSTR + 16 * bx + w;
      laB[addr] = (float)((m >> c) & 1u);
      prB[addr] = __builtin_amdgcn_rcpf(1.f + __expf(-v)) + 1e-6f;
    }
  }

  if (tid == 0) {
    const int slot = (bx + 11 * (wy + 171 * b)) & 63;
    float* dst = ws + WS_RED + slot * 16;
    atomicAdd(&dst[0], sRed[0][0] + sRed[0][1] + sRed[0][2]);
    atomicAdd(&dst[1], sRed[1][0] + sRed[1][1] + sRed[1][2]);
    atomicAdd(&dst[2], sRed[2][0] + sRed[2][1] + sRed[2][2]);
    atomicAdd(&dst[3], sRed[3][0] + sRed[3][1] + sRed[3][2]);
  }
}

__global__ __launch_bounds__(192)
void kA(const float* __restrict__ cls, const int* __restrict__ label,
        float* __restrict__ ws) {
  __shared__ __align__(16) float sPixF[NCHT * 144];
  __shared__ unsigned sMask[144];
  __shared__ float    sRed[4][3];
  const int bx = blockIdx.x, wy = blockIdx.y, b = blockIdx.z;
  if (bx < 10)
    kA_body<12>(bx, wy, b, threadIdx.x, cls, label, ws, sPixF, sMask, sRed);
  else
    kA_body<8>(bx, wy, b, threadIdx.x, cls, label, ws, sPixF, sMask, sRed);
}

// ---------------- kernel Cov: sliding window, 4 roles, NO atomics -----------
// R20: R19 was atomic-writeback-bound (WRITE_SIZE 59MB from 307k device-scope
// RMWs bouncing lines across XCDs; hbm_bytes 90MB at 1.1TB/s = the 79us).
// Roles now write wave-reduced partials as plain contiguous stores into
// part[bc][chunk][192]; kRed sums 14 chunks -> cov/s1 (kSolve unchanged).
// Entry map: e<45 AA-up | 45..80 AP rows0-3 | 81..125 AP rows4-8 |
// 126..170 PP-up | 171..179 sumsA | 180..188 sumsP.
template <int R>
__device__ __forceinline__ void covRole(
    const float* __restrict__ laP, const float* __restrict__ prP,
    const int rbase, const int lane, float* __restrict__ pp) {
  constexpr int NACC = (R == 1) ? 36 : 45;
  constexpr bool needA = (R <= 2);
  constexpr bool needP = (R >= 1);

  float acc[NACC];
  #pragma unroll
  for (int k = 0; k < NACC; k++) acc[k] = 0.f;
  float sums[9];
  #pragma unroll
  for (int k = 0; k < 9; k++) sums[k] = 0.f;

  for (int cb = 0; cb < 3; cb++) {
    const int sx  = 62 * cb + lane;
    const int sxc = (sx < 169) ? sx : 169;
    const float okf = (lane < 62 && sx < NHW) ? 1.f : 0.f;
    const float* lc0 = laP + sxc;
    const float* pc0 = prP + sxc;

    float A[9], P[9];
    if (needA) {
      float x = lc0[(size_t)(rbase + 0) * RSTR];
      A[0] = x * okf; A[1] = __shfl_down(x, 1) * okf; A[2] = __shfl_down(x, 2) * okf;
      x = lc0[(size_t)(rbase + 1) * RSTR];
      A[3] = x * okf; A[4] = __shfl_down(x, 1) * okf; A[5] = __shfl_down(x, 2) * okf;
    }
    if (needP) {
      float x = pc0[(size_t)(rbase + 0) * RSTR];
      P[0] = x * okf; P[1] = __shfl_down(x, 1) * okf; P[2] = __shfl_down(x, 2) * okf;
      x = pc0[(size_t)(rbase + 1) * RSTR];
      P[3] = x * okf; P[4] = __shfl_down(x, 1) * okf; P[5] = __shfl_down(x, 2) * okf;
    }
    #pragma unroll
    for (int ii = 0; ii < 12; ii++) {
      const int r = rbase + ii;
      if (needA) {
        float x = lc0[(size_t)(r + 2) * RSTR];
        A[6] = x * okf; A[7] = __shfl_down(x, 1) * okf; A[8] = __shfl_down(x, 2) * okf;
      }
      if (needP) {
        float x = pc0[(size_t)(r + 2) * RSTR];
        P[6] = x * okf; P[7] = __shfl_down(x, 1) * okf; P[8] = __shfl_down(x, 2) * okf;
      }

      if (R == 0) {
        int q = 0;
        #pragma unroll
        for (int i = 0; i < 9; i++)
          #pragma unroll
          for (int j = i; j < 9; j++) { acc[q] = fmaf(A[i], A[j], acc[q]); q++; }
        #pragma unroll
        for (int k = 0; k < 9; k++) sums[k] += A[k];
      } else if (R == 1) {
        int q = 0;
        #pragma unroll
        for (int i = 0; i < 4; i++)
          #pragma unroll
          for (int j = 0; j < 9; j++) { acc[q] = fmaf(A[i], P[j], acc[q]); q++; }
      } else if (R == 2) {
        int q = 0;
        #pragma unroll
        for (int i = 4; i < 9; i++)
          #pragma unroll
          for (int j = 0; j < 9; j++) { acc[q] = fmaf(A[i], P[j], acc[q]); q++; }
      } else {
        int q = 0;
        #pragma unroll
        for (int i = 0; i < 9; i++)
          #pragma unroll
          for (int j = i; j < 9; j++) { acc[q] = fmaf(P[i], P[j], acc[q]); q++; }
        #pragma unroll
        for (int k = 0; k < 9; k++) sums[k] += P[k];
      }

      if (needA) {
        #pragma unroll
        for (int k = 0; k < 6; k++) A[k] = A[k + 3];
      }
      if (needP) {
        #pragma unroll
        for (int k = 0; k < 6; k++) P[k] = P[k + 3];
      }
    }
  }

  #pragma unroll
  for (int k = 0; k < NACC; k++) {
    float v = acc[k];
    #pragma unroll
    for (int m = 32; m >= 1; m >>= 1) v += __shfl_xor(v, m);
    acc[k] = v;
  }
  if (R == 0 || R == 3) {
    #pragma unroll
    for (int k = 0; k < 9; k++) {
      float v = sums[k];
      #pragma unroll
      for (int m = 32; m >= 1; m >>= 1) v += __shfl_xor(v, m);
      sums[k] = v;
    }
  }

  if (lane == 0) {
    constexpr int base = (R == 0) ? 0 : ((R == 1) ? 45 : ((R == 2) ? 81 : 126));
    #pragma unroll
    for (int k = 0; k < NACC; k++) pp[base + k] = acc[k];
    if (R == 0) {
      #pragma unroll
      for (int k = 0; k < 9; k++) pp[171 + k] = sums[k];
    } else if (R == 3) {
      #pragma unroll
      for (int k = 0; k < 9; k++) pp[180 + k] = sums[k];
    }
  }
}

__global__ __launch_bounds__(256, 5)
void kCov(const float* __restrict__ ws_base, float* __restrict__ part) {
  const int bc    = blockIdx.x;
  const int chunk = blockIdx.y;
  const int tid   = threadIdx.x;
  const int lane  = tid & 63;
  const int role  = tid >> 6;          // 0..3
  const int rbase = chunk * 12;

  const float* laP = ws_base + WS_LA + (size_t)bc * PH * RSTR;
  const float* prP = ws_base + WS_PR + (size_t)bc * PH * RSTR;
  float* pp = part + (size_t)(bc * CCH + chunk) * PSTR;

  if (role == 0)      covRole<0>(laP, prP, rbase, lane, pp);
  else if (role == 1) covRole<1>(laP, prP, rbase, lane, pp);
  else if (role == 2) covRole<2>(laP, prP, rbase, lane, pp);
  else                covRole<3>(laP, prP, rbase, lane, pp);
}

// ---------------- kernel Red: sum 14 chunk-partials -> cov + s1 -------------
__global__ __launch_bounds__(192)
void kRed(const float* __restrict__ part, float* __restrict__ cov,
          float* __restrict__ s1out) {
  const int bc = blockIdx.x;
  const int e  = threadIdx.x;
  if (e >= 189) return;
  const float* p = part + (size_t)bc * CCH * PSTR + e;
  float s = 0.f;
  #pragma unroll
  for (int c = 0; c < CCH; c++) s += p[c * PSTR];

  if (e < 171) {
    int i, j;
    if (e < 45) {
      int q = e; i = 0;
      while (q >= 9 - i) { q -= 9 - i; i++; }
      j = i + q;
    } else if (e < 81) {
      const int q = e - 45; i = q / 9; j = 9 + q % 9;
    } else if (e < 126) {
      const int q = e - 81; i = 4 + q / 9; j = 9 + q % 9;
    } else {
      int q = e - 126; i = 0;
      while (q >= 9 - i) { q -= 9 - i; i++; }
      j = i + q; i += 9; j += 9;
    }
    cov[(size_t)bc * 324 + i * 18 + j] = s;
  } else if (e < 180) {
    s1out[bc * 32 + (e - 171)] = s;
  } else {
    s1out[bc * 32 + 9 + (e - 180)] = s;
  }
}

// ---------------- kernel Solve: one wave per (b,c); center in DOUBLE --------
__global__ __launch_bounds__(64)
void kSolve(const float* __restrict__ cov_all, const float* __restrict__ s1,
            float* __restrict__ acc) {
  const int bc   = blockIdx.x;
  const int lane = threadIdx.x;
  const float* cr = cov_all + (size_t)bc * 324;
  const double n = (double)NS;

  double mu[18];
  #pragma unroll
  for (int r = 0; r < 18; r++) mu[r] = (double)s1[bc * 32 + r] / n;
#define CC(i, j) ((double)cr[(i) * 18 + (j)] - n * mu[(i)] * mu[(j)])

  double row[9];
  #pragma unroll
  for (int j = 0; j < 9; j++)
    row[j] = (lane < 9 && j <= lane) ? CC(9 + j, 9 + lane) : 0.0;
  if (lane < 9) row[lane] += 1e-3;

  #pragma unroll
  for (int k = 0; k < 9; k++) {
    if (lane == k) {
      double s = row[k];
      #pragma unroll
      for (int m = 0; m < k; m++) s -= row[m] * row[m];
      row[k] = sqrt(fmax(s, 1e-300));
    }
    double rk[9];
    #pragma unroll
    for (int m = 0; m <= k; m++) rk[m] = __shfl(row[m], k);
    if (lane > k && lane < 9) {
      double s = row[k];
      #pragma unroll
      for (int m = 0; m < k; m++) s -= row[m] * rk[m];
      row[k] = s / rk[k];
    }
  }

  double Lm[9][9];
  #pragma unroll
  for (int i = 0; i < 9; i++)
    #pragma unroll
    for (int m = 0; m <= i; m++) Lm[i][m] = __shfl(row[m], i);

  double mc[9];
  #pragma unroll
  for (int r = 0; r < 9; r++) mc[r] = 0.0;
  if (lane < 9) {
    #pragma unroll
    for (int r = 0; r < 9; r++) {
      double s = CC(lane, 9 + r);
      #pragma unroll
      for (int m = 0; m < r; m++) s -= Lm[r][m] * mc[m];
      mc[r] = s / Lm[r][r];
    }
  }

  double a2[9];
  #pragma unroll
  for (int j = 0; j < 9; j++) a2[j] = 0.0;
  #pragma unroll
  for (int j = 0; j < 9; j++) {
    double mj[9];
    #pragma unroll
    for (int r = 0; r < 9; r++) mj[r] = __shfl(mc[r], j);
    double dot = 0.0;
    #pragma unroll
    for (int r = 0; r < 9; r++) dot += mc[r] * mj[r];
    if (lane < 9 && j <= lane)
      a2[j] = CC(j, lane) - dot + ((j == lane) ? 1e-3 : 0.0);
  }
#undef CC

  double myld = 0.0;
  #pragma unroll
  for (int k = 0; k < 9; k++) {
    if (lane == k) {
      double s = a2[k];
      #pragma unroll
      for (int m = 0; m < k; m++) s -= a2[m] * a2[m];
      double d = sqrt(fmax(s, 0.0));
      a2[k] = d;
      myld = 2.0 * log(d + 1e-8);
    }
    double rk[9];
    #pragma unroll
    for (int m = 0; m <= k; m++) rk[m] = __shfl(a2[m], k);
    if (lane > k && lane < 9) {
      double s = a2[k];
      #pragma unroll
      for (int m = 0; m < k; m++) s -= a2[m] * rk[m];
      a2[k] = s / rk[k];
    }
  }
  #pragma unroll
  for (int m = 32; m >= 1; m >>= 1) myld += __shfl_xor(myld, m);
  if (lane == 0) atomicAdd(&acc[4], (float)myld);
}

// ---------------- finalize: reduce 64 BCE slots + combine --------------------
__global__ void kFin(const float* __restrict__ ws, float* __restrict__ out) {
  const int tid = threadIdx.x;
  const float* slot = ws + WS_RED + tid * 16;
  float b0 = slot[0], b1 = slot[1], b2 = slot[2], b3 = slot[3];
  #pragma unroll
  for (int m = 32; m >= 1; m >>= 1) {
    b0 += __shfl_xor(b0, m);
    b1 += __shfl_xor(b1, m);
    b2 += __shfl_xor(b2, m);
    b3 += __shfl_xor(b3, m);
  }
  if (tid == 0) {
    const double cnt = (double)b3;
    const double bce = 0.5 * ((double)b0 / (cnt * NF + 1e-8) +
                              (double)b1 / (cnt * NM + 1e-8) +
                              (double)b2 / (cnt * NHI + 1e-8));
    const double rmi = 0.5 * (double)ws[4] / (double)(NB * 9);
    out[0] = (float)(bce + rmi);
  }
}

extern "C" void kernel_launch(void* const* d_in, const int* in_sizes, int n_in,
                              void* d_out, int out_size, void* d_ws, size_t ws_size,
                              hipStream_t stream) {
  (void)in_sizes; (void)n_in; (void)out_size; (void)ws_size;
  const float* cls   = (const float*)d_in[3];
  const int*   label = (const int*)d_in[4];
  float* ws = (float*)d_ws;

  hipMemsetAsync(d_ws, 0, WS_ZERO_BYTES, stream);

  dim3 gA(11, 171, NB);
  kA<<<gA, 192, 0, stream>>>(cls, label, ws);
  kCov<<<dim3(NBC, CCH), 256, 0, stream>>>(ws, ws + WS_PART);
  kRed<<<NBC, 192, 0, stream>>>(ws + WS_PART, ws + WS_COV, ws + WS_S1);
  kSolve<<<NBC, 64, 0, stream>>>(ws + WS_COV, ws + WS_S1, ws);
  kFin<<<1, 64, 0, stream>>>(ws, (float*)d_out);
}